// Round 1
// 1005.730 us; speedup vs baseline: 1.0736x; 1.0736x over previous
//
#include <hip/hip_runtime.h>
#include <hip/hip_bf16.h>

typedef unsigned short u16;
typedef __bf16 bf16_t;
typedef _Float16 half_t;
typedef __bf16 v8bf __attribute__((ext_vector_type(8)));
typedef _Float16 v8h __attribute__((ext_vector_type(8)));
typedef float v4fl __attribute__((ext_vector_type(4)));
typedef float v4f __attribute__((ext_vector_type(4)));

#define BM 128
#define BN 128
#define BK 32

__device__ __forceinline__ float ternq(float w, float s) {
    float q = rintf(w / s);                 // true division: match jnp boundary
    return fminf(1.f, fmaxf(-1.f, q));
}

// async global->LDS, 16 bytes per lane. LDS dest is wave-uniform base + lane*16,
// so the LDS layout must be linear in lane order (it is: chunk = i*256 + tid).
__device__ __forceinline__ void gload16(const void* g, void* l) {
    __builtin_amdgcn_global_load_lds(
        (const __attribute__((address_space(1))) void*)g,
        (__attribute__((address_space(3))) void*)l, 16, 0, 0);
}

// ---------------- stage 1: per-block partial sum of |w| (deterministic) ----------
__global__ void abssum_partial(const float* __restrict__ w, long n,
                               float* __restrict__ partial) {
    long i0 = ((long)blockIdx.x * 256 + threadIdx.x) * 8;
    long stride = (long)gridDim.x * 256 * 8;
    float s = 0.f;
    for (long i = i0; i < n; i += stride) {
        v4fl a = *(const v4fl*)(w + i);
        v4fl b = *(const v4fl*)(w + i + 4);
#pragma unroll
        for (int j = 0; j < 4; ++j) s += fabsf(a[j]) + fabsf(b[j]);
    }
#pragma unroll
    for (int off = 32; off > 0; off >>= 1) s += __shfl_down(s, off, 64);
    __shared__ __align__(16) float red[4];
    if ((threadIdx.x & 63) == 0) red[threadIdx.x >> 6] = s;
    __syncthreads();
    if (threadIdx.x == 0)
        partial[blockIdx.x] = (red[0] + red[1]) + (red[2] + red[3]);
}

// ---------------- stage 2: combine 256 partials per matrix, fixed order -----------
__global__ void abssum_final(const float* __restrict__ part_up,
                             const float* __restrict__ part_dn,
                             float* __restrict__ scales, float inv) {
    const int wv = threadIdx.x >> 6;
    const int l = threadIdx.x & 63;
    const float* part = wv ? part_dn : part_up;
    float s = ((part[l] + part[l + 64]) + (part[l + 128] + part[l + 192]));
#pragma unroll
    for (int off = 32; off > 0; off >>= 1) s += __shfl_down(s, off, 64);
    if (l == 0) scales[wv] = fmaxf(s * inv, 1e-5f);
}

// ---------------- ternary weight quant fp32 -> bf16 {-1,0,1} ----------------
__global__ void wquant_kernel(const float* __restrict__ w, u16* __restrict__ wq,
                              const float* __restrict__ scale) {
    float s = scale[0];
    long i = ((long)blockIdx.x * 256 + threadIdx.x) * 8;
    v4fl a = *(const v4fl*)(w + i);
    v4fl b = *(const v4fl*)(w + i + 4);
    v8bf o;
#pragma unroll
    for (int j = 0; j < 4; ++j) {
        o[j]     = (bf16_t)ternq(a[j], s);
        o[j + 4] = (bf16_t)ternq(b[j], s);
    }
    *(v8bf*)(wq + i) = o;
}

// ---------------- per-token act quant fp32 -> bf16 ints, width 2048 ----------------
__global__ void aquant_kernel(const float* __restrict__ src, u16* __restrict__ dst,
                              float* __restrict__ scale_out) {
    const int row = blockIdx.x;
    const int tid = threadIdx.x;
    const float* p = src + (size_t)row * 2048;
    float v[8];
    {
        v4fl a = *(const v4fl*)(p + tid * 8);
        v4fl b = *(const v4fl*)(p + tid * 8 + 4);
#pragma unroll
        for (int j = 0; j < 4; ++j) { v[j] = a[j]; v[j + 4] = b[j]; }
    }
    float amax = 0.f;
#pragma unroll
    for (int j = 0; j < 8; ++j) amax = fmaxf(amax, fabsf(v[j]));
#pragma unroll
    for (int off = 32; off > 0; off >>= 1) amax = fmaxf(amax, __shfl_xor(amax, off, 64));
    __shared__ __align__(16) float red[4];
    __shared__ float bsc;
    if ((tid & 63) == 0) red[tid >> 6] = amax;
    __syncthreads();
    if (tid == 0) {
        float m = fmaxf(fmaxf(red[0], red[1]), fmaxf(red[2], red[3]));
        m = fmaxf(m, 1e-5f);
        scale_out[row] = m / 127.f;
        bsc = 127.f / m;
    }
    __syncthreads();
    float sc = bsc;
    v8bf o;
#pragma unroll
    for (int j = 0; j < 8; ++j) {
        float t = rintf(v[j] * sc);
        o[j] = (bf16_t)fminf(127.f, fmaxf(-127.f, t));
    }
    *(v8bf*)(dst + (size_t)row * 2048 + tid * 8) = o;
}

// ---------------- fused per-row amax + quantize of h: fp32 -> bf16 ints -----------
// One block per row, width = NV*2048. Row lives in regs: one global read pass.
// Identical math to the old quantize-on-stage path (same fp32 amax, same rint/clip).
template <int NV>
__global__ void hquant_kernel(const float* __restrict__ h, u16* __restrict__ hq,
                              float* __restrict__ scale_out) {
    const int row = blockIdx.x;
    const int tid = threadIdx.x;
    const int W = NV * 2048;
    const float* p = h + (size_t)row * W + tid * (NV * 8);
    float v[NV * 8];
#pragma unroll
    for (int it = 0; it < NV * 2; ++it) {
        v4fl a = *(const v4fl*)(p + it * 4);
#pragma unroll
        for (int j = 0; j < 4; ++j) v[it * 4 + j] = a[j];
    }
    float amax = 0.f;
#pragma unroll
    for (int j = 0; j < NV * 8; ++j) amax = fmaxf(amax, fabsf(v[j]));
#pragma unroll
    for (int off = 32; off > 0; off >>= 1) amax = fmaxf(amax, __shfl_xor(amax, off, 64));
    __shared__ __align__(16) float red[4];
    __shared__ float bsc;
    if ((tid & 63) == 0) red[tid >> 6] = amax;
    __syncthreads();
    if (tid == 0) {
        float m = fmaxf(fmaxf(red[0], red[1]), fmaxf(red[2], red[3]));
        m = fmaxf(m, 1e-5f);
        scale_out[row] = m / 127.f;
        bsc = 127.f / m;
    }
    __syncthreads();
    const float sc = bsc;
    u16* dst = hq + (size_t)row * W + tid * (NV * 8);
#pragma unroll
    for (int it = 0; it < NV; ++it) {
        v8bf o;
#pragma unroll
        for (int j = 0; j < 8; ++j) {
            float t = rintf(v[it * 8 + j] * sc);
            o[j] = (bf16_t)fminf(127.f, fmaxf(-127.f, t));
        }
        *(v8bf*)(dst + it * 8) = o;
    }
}

// ---------------- per-row amax of h (fallback paths only) -------------------------
template <typename T, int NV>
__global__ void hamax_kernel(const T* __restrict__ h, float* __restrict__ scale_out,
                             float* __restrict__ recip_out) {
    const int row = blockIdx.x;
    const int tid = threadIdx.x;
    const T* p = h + (size_t)row * (NV * 2048);
    float amax = 0.f;
#pragma unroll
    for (int it = 0; it < NV; ++it) {
        const T* s = p + ((size_t)it * 256 + tid) * 8;
#pragma unroll
        for (int j = 0; j < 8; ++j) amax = fmaxf(amax, fabsf((float)s[j]));
    }
#pragma unroll
    for (int off = 32; off > 0; off >>= 1) amax = fmaxf(amax, __shfl_xor(amax, off, 64));
    __shared__ __align__(16) float red[4];
    if ((tid & 63) == 0) red[tid >> 6] = amax;
    __syncthreads();
    if (tid == 0) {
        float m = fmaxf(fmaxf(red[0], red[1]), fmaxf(red[2], red[3]));
        m = fmaxf(m, 1e-5f);
        scale_out[row] = m / 127.f;
        recip_out[row] = 127.f / m;
    }
}

// ---------------- GEMM: C[M,N] = A[M,K] * B[N,K]^T -> MFMA bf16 ----------------
// m97 structure: 128x128 tile, BK=32, global_load_lds width-16 staging, 2 barriers/K.
// ASRC: 0 = A bf16 ints via global_load_lds; 1 = A fp32 quantize-on-stage (reg path);
//       2 = A fp16 quantize-on-stage.
// EPI:  0 = out fp32 = acc*sw*rowscale; 1 = h fp16 = relu(...)^2; 2 = h fp32 = relu(...)^2.
template <int ASRC, int EPI>
__launch_bounds__(256, 2)
__global__ void gemm_bt(const void* __restrict__ Av, const u16* __restrict__ B,
                        void* __restrict__ Cv,
                        const float* __restrict__ rowscale,
                        const float* __restrict__ arecip,
                        const float* __restrict__ wscale,
                        int M, int N, int K) {
    __shared__ __align__(16) u16 As[BM * BK];   // 8 KB, linear [128][32]
    __shared__ __align__(16) u16 Bs[BN * BK];   // 8 KB

    const int tid = threadIdx.x;

    // XCD-aware bijective swizzle of the flattened block id (nwg % 8 == 0 here)
    const int gx = gridDim.x;
    const int nwg = gx * gridDim.y;
    int flat = blockIdx.y * gx + blockIdx.x;
    if ((nwg & 7) == 0) flat = (flat & 7) * (nwg >> 3) + (flat >> 3);
    const int n0 = (flat % gx) * BN;
    const int m0 = (flat / gx) * BM;

    // ---- staging addressing: chunk c = i*256 + tid; row = c>>2, col = (c&3)*8 ----
    const int srow = tid >> 2;              // 0..63
    const int scol = (tid & 3) * 8;
    const u16* gB0 = B + (size_t)(n0 + srow) * K + scol;
    const u16* gB1 = B + (size_t)(n0 + 64 + srow) * K + scol;
    u16* lB0 = Bs + tid * 8;
    u16* lB1 = Bs + 2048 + tid * 8;

    const u16* gA0 = nullptr;
    const u16* gA1 = nullptr;
    u16* lA0 = As + tid * 8;
    u16* lA1 = As + 2048 + tid * 8;
    if (ASRC == 0) {
        gA0 = (const u16*)Av + (size_t)(m0 + srow) * K + scol;
        gA1 = (const u16*)Av + (size_t)(m0 + 64 + srow) * K + scol;
    }

    // reg-stage quantize path (fallbacks): thread owns row tid>>1, 16 cols at (tid&1)*16
    const int qrow = tid >> 1;
    const int qcol = (tid & 1) * 16;
    const float* gA32 = (const float*)Av + (size_t)(m0 + qrow) * K + qcol;
    const half_t* gAh = (const half_t*)Av + (size_t)(m0 + qrow) * K + qcol;
    u16* qdst = As + qrow * BK + qcol;
    const float qsc = (ASRC != 0) ? arecip[m0 + qrow] : 0.f;

    // compute role: wave (wr,wc) owns 64x64; 4x4 of 16x16x32 tiles
    const int w = tid >> 6, l = tid & 63;
    const int wr = w >> 1, wc = w & 1;
    const int lrow = l & 15, lq = l >> 4;

    v4f acc[4][4];
#pragma unroll
    for (int a = 0; a < 4; ++a)
#pragma unroll
        for (int b = 0; b < 4; ++b) acc[a][b] = (v4f){0.f, 0.f, 0.f, 0.f};

    const int kiters = K / BK;
    for (int kt = 0; kt < kiters; ++kt) {
        const int off = kt * BK;
        v8bf r0, r1;
        if (ASRC == 1) {
            v4fl f0 = *(const v4fl*)(gA32 + off);
            v4fl f1 = *(const v4fl*)(gA32 + off + 4);
            v4fl f2 = *(const v4fl*)(gA32 + off + 8);
            v4fl f3 = *(const v4fl*)(gA32 + off + 12);
#pragma unroll
            for (int e = 0; e < 4; ++e) {
                r0[e]     = (bf16_t)fminf(127.f, fmaxf(-127.f, rintf(f0[e] * qsc)));
                r0[e + 4] = (bf16_t)fminf(127.f, fmaxf(-127.f, rintf(f1[e] * qsc)));
                r1[e]     = (bf16_t)fminf(127.f, fmaxf(-127.f, rintf(f2[e] * qsc)));
                r1[e + 4] = (bf16_t)fminf(127.f, fmaxf(-127.f, rintf(f3[e] * qsc)));
            }
        } else if (ASRC == 2) {
            v8h h0 = *(const v8h*)(gAh + off);
            v8h h1 = *(const v8h*)(gAh + off + 8);
#pragma unroll
            for (int e = 0; e < 8; ++e) {
                r0[e] = (bf16_t)fminf(127.f, fmaxf(-127.f, rintf((float)h0[e] * qsc)));
                r1[e] = (bf16_t)fminf(127.f, fmaxf(-127.f, rintf((float)h1[e] * qsc)));
            }
        }
        __syncthreads();                       // all fragment reads of prev tile done
        gload16(gB0 + off, lB0);
        gload16(gB1 + off, lB1);
        if (ASRC == 0) {
            gload16(gA0 + off, lA0);
            gload16(gA1 + off, lA1);
        } else {
            *(v8bf*)qdst = r0;
            *(v8bf*)(qdst + 8) = r1;
        }
        __syncthreads();                       // compiler drains vmcnt/lgkm before barrier

        v8bf af[4], bfr[4];
#pragma unroll
        for (int mi = 0; mi < 4; ++mi)
            af[mi] = *(const v8bf*)(As + (wr * 64 + mi * 16 + lrow) * BK + lq * 8);
#pragma unroll
        for (int nj = 0; nj < 4; ++nj)
            bfr[nj] = *(const v8bf*)(Bs + (wc * 64 + nj * 16 + lrow) * BK + lq * 8);
#pragma unroll
        for (int mi = 0; mi < 4; ++mi)
#pragma unroll
            for (int nj = 0; nj < 4; ++nj)
                acc[mi][nj] = __builtin_amdgcn_mfma_f32_16x16x32_bf16(
                    af[mi], bfr[nj], acc[mi][nj], 0, 0, 0);
    }

    const float sw = wscale[0];   // pre-clipped mean|w|
#pragma unroll
    for (int mi = 0; mi < 4; ++mi) {
#pragma unroll
        for (int r = 0; r < 4; ++r) {
            const int row = m0 + wr * 64 + mi * 16 + lq * 4 + r;
            const float rs = sw * rowscale[row];
#pragma unroll
            for (int nj = 0; nj < 4; ++nj) {
                const int col = n0 + wc * 64 + nj * 16 + lrow;
                float v = acc[mi][nj][r] * rs;
                if (EPI == 0) {
                    ((float*)Cv)[(size_t)row * N + col] = v;
                } else if (EPI == 1) {
                    v = fmaxf(v, 0.f); v = v * v;
                    ((half_t*)Cv)[(size_t)row * N + col] = (half_t)v;
                } else {
                    v = fmaxf(v, 0.f); v = v * v;
                    ((float*)Cv)[(size_t)row * N + col] = v;
                }
            }
        }
    }
}

extern "C" void kernel_launch(void* const* d_in, const int* in_sizes, int n_in,
                              void* d_out, int out_size, void* d_ws, size_t ws_size,
                              hipStream_t stream) {
    const float* x   = (const float*)d_in[0];   // [T, H] fp32
    const float* wup = (const float*)d_in[1];   // [I, H] fp32
    const float* wdn = (const float*)d_in[2];   // [H, I] fp32

    const int H = 2048;
    const int T = in_sizes[0] / H;              // 16384
    const int I = in_sizes[1] / H;              // 4096
    const long nw = (long)in_sizes[1];          // 8388608
    const float winv = 1.0f / (float)nw;

    char* p = (char*)d_ws;
    float* scales  = (float*)p;                 // 2 floats (pre-clipped s_up, s_dn)
    float* part_up = (float*)(p + 256);         // 256 floats
    float* part_dn = (float*)(p + 1280);        // 256 floats
    float* a_scale = (float*)(p + 2304);        // T
    float* h_scale = a_scale + T;               // T
    float* h_recip = h_scale + T;               // T
    size_t off = 2304 + (size_t)12 * T;
    off = (off + 255) & ~(size_t)255;
    u16* xq  = (u16*)(p + off); off += (size_t)T * H * 2;
    u16* wqu = (u16*)(p + off); off += (size_t)I * H * 2;
    u16* wqd = (u16*)(p + off); off += (size_t)H * I * 2;
    void* h  = (void*)(p + off);
    u16* hq  = (u16*)(p + off + (size_t)T * I * 4);

    const size_t need_full = off + (size_t)T * I * 6;   // h fp32 + hq bf16
    const size_t need_h32  = off + (size_t)T * I * 4;   // h fp32 only
    const int mode = (ws_size == 0 || need_full <= ws_size) ? 0
                   : (need_h32 <= ws_size ? 1 : 2);

    // deterministic mean|w|: per-block partials, then fixed-order combine
    abssum_partial<<<256, 256, 0, stream>>>(wup, nw, part_up);
    abssum_partial<<<256, 256, 0, stream>>>(wdn, nw, part_dn);
    abssum_final<<<1, 128, 0, stream>>>(part_up, part_dn, scales, winv);

    int wblocks = (int)(nw / 2048);
    wquant_kernel<<<wblocks, 256, 0, stream>>>(wup, wqu, scales + 0);
    wquant_kernel<<<wblocks, 256, 0, stream>>>(wdn, wqd, scales + 1);

    aquant_kernel<<<T, 256, 0, stream>>>(x, xq, a_scale);

    if (mode == 0) {
        gemm_bt<0, 2><<<dim3(I / BN, T / BM), 256, 0, stream>>>(
            xq, wqu, h, a_scale, nullptr, scales + 0, T, I, H);
        hquant_kernel<2><<<T, 256, 0, stream>>>((const float*)h, hq, h_scale);
        gemm_bt<0, 0><<<dim3(H / BN, T / BM), 256, 0, stream>>>(
            hq, wqd, d_out, h_scale, nullptr, scales + 1, T, H, I);
    } else if (mode == 1) {
        gemm_bt<0, 2><<<dim3(I / BN, T / BM), 256, 0, stream>>>(
            xq, wqu, h, a_scale, nullptr, scales + 0, T, I, H);
        hamax_kernel<float, 2><<<T, 256, 0, stream>>>((const float*)h, h_scale, h_recip);
        gemm_bt<1, 0><<<dim3(H / BN, T / BM), 256, 0, stream>>>(
            h, wqd, d_out, h_scale, h_recip, scales + 1, T, H, I);
    } else {
        gemm_bt<0, 1><<<dim3(I / BN, T / BM), 256, 0, stream>>>(
            xq, wqu, h, a_scale, nullptr, scales + 0, T, I, H);
        hamax_kernel<half_t, 2><<<T, 256, 0, stream>>>((const half_t*)h, h_scale, h_recip);
        gemm_bt<2, 0><<<dim3(H / BN, T / BM), 256, 0, stream>>>(
            h, wqd, d_out, h_scale, h_recip, scales + 1, T, H, I);
    }
}

// Round 2
// 677.326 us; speedup vs baseline: 1.5941x; 1.4849x over previous
//
#include <hip/hip_runtime.h>
#include <hip/hip_bf16.h>

typedef unsigned short u16;
typedef signed char i8_t;
typedef _Float16 half_t;
typedef float v4fl __attribute__((ext_vector_type(4)));
typedef _Float16 v8h __attribute__((ext_vector_type(8)));
typedef int v4i __attribute__((ext_vector_type(4)));
typedef signed char v8c __attribute__((ext_vector_type(8)));
typedef signed char v16c __attribute__((ext_vector_type(16)));

#define BM 128
#define BN 128
#define BK 64   // i8 elements per K-step (64 bytes/row, same LDS bytes/step as bf16 BK=32)

__device__ __forceinline__ float ternqf(float w, float s) {
    float q = rintf(w / s);                 // true division: match jnp boundary
    return fminf(1.f, fmaxf(-1.f, q));
}

// async global->LDS, 16 bytes per lane. LDS dest is wave-uniform base + lane*16,
// so the LDS layout must be linear in lane order (it is: chunk = i*256 + tid).
__device__ __forceinline__ void gload16(const void* g, void* l) {
    __builtin_amdgcn_global_load_lds(
        (const __attribute__((address_space(1))) void*)g,
        (__attribute__((address_space(3))) void*)l, 16, 0, 0);
}

// ---------------- stage 1: per-block partial sum of |w| (deterministic) ----------
__global__ void abssum_partial(const float* __restrict__ w, long n,
                               float* __restrict__ partial) {
    long i0 = ((long)blockIdx.x * 256 + threadIdx.x) * 8;
    long stride = (long)gridDim.x * 256 * 8;
    float s = 0.f;
    for (long i = i0; i < n; i += stride) {
        v4fl a = *(const v4fl*)(w + i);
        v4fl b = *(const v4fl*)(w + i + 4);
#pragma unroll
        for (int j = 0; j < 4; ++j) s += fabsf(a[j]) + fabsf(b[j]);
    }
#pragma unroll
    for (int off = 32; off > 0; off >>= 1) s += __shfl_down(s, off, 64);
    __shared__ __align__(16) float red[4];
    if ((threadIdx.x & 63) == 0) red[threadIdx.x >> 6] = s;
    __syncthreads();
    if (threadIdx.x == 0)
        partial[blockIdx.x] = (red[0] + red[1]) + (red[2] + red[3]);
}

// ---------------- stage 2: combine 256 partials per matrix, fixed order -----------
__global__ void abssum_final(const float* __restrict__ part_up,
                             const float* __restrict__ part_dn,
                             float* __restrict__ scales, float inv) {
    const int wv = threadIdx.x >> 6;
    const int l = threadIdx.x & 63;
    const float* part = wv ? part_dn : part_up;
    float s = ((part[l] + part[l + 64]) + (part[l + 128] + part[l + 192]));
#pragma unroll
    for (int off = 32; off > 0; off >>= 1) s += __shfl_down(s, off, 64);
    if (l == 0) scales[wv] = fmaxf(s * inv, 1e-5f);
}

// ---------------- ternary weight quant fp32 -> i8 {-1,0,1} ----------------
__global__ void wquant_kernel(const float* __restrict__ w, i8_t* __restrict__ wq,
                              const float* __restrict__ scale) {
    float s = scale[0];
    long i = ((long)blockIdx.x * 256 + threadIdx.x) * 8;
    v4fl a = *(const v4fl*)(w + i);
    v4fl b = *(const v4fl*)(w + i + 4);
    v8c o;
#pragma unroll
    for (int j = 0; j < 4; ++j) {
        o[j]     = (i8_t)(int)ternqf(a[j], s);
        o[j + 4] = (i8_t)(int)ternqf(b[j], s);
    }
    *(v8c*)(wq + i) = o;
}

// ---------------- per-token act quant fp32 -> i8 ints, width 2048 ----------------
__global__ void aquant_kernel(const float* __restrict__ src, i8_t* __restrict__ dst,
                              float* __restrict__ scale_out) {
    const int row = blockIdx.x;
    const int tid = threadIdx.x;
    const float* p = src + (size_t)row * 2048;
    float v[8];
    {
        v4fl a = *(const v4fl*)(p + tid * 8);
        v4fl b = *(const v4fl*)(p + tid * 8 + 4);
#pragma unroll
        for (int j = 0; j < 4; ++j) { v[j] = a[j]; v[j + 4] = b[j]; }
    }
    float amax = 0.f;
#pragma unroll
    for (int j = 0; j < 8; ++j) amax = fmaxf(amax, fabsf(v[j]));
#pragma unroll
    for (int off = 32; off > 0; off >>= 1) amax = fmaxf(amax, __shfl_xor(amax, off, 64));
    __shared__ __align__(16) float red[4];
    __shared__ float bsc;
    if ((tid & 63) == 0) red[tid >> 6] = amax;
    __syncthreads();
    if (tid == 0) {
        float m = fmaxf(fmaxf(red[0], red[1]), fmaxf(red[2], red[3]));
        m = fmaxf(m, 1e-5f);
        scale_out[row] = m / 127.f;
        bsc = 127.f / m;
    }
    __syncthreads();
    float sc = bsc;
    v8c o;
#pragma unroll
    for (int j = 0; j < 8; ++j) {
        float t = rintf(v[j] * sc);
        o[j] = (i8_t)(int)fminf(127.f, fmaxf(-127.f, t));
    }
    *(v8c*)(dst + (size_t)row * 2048 + tid * 8) = o;
}

// ---------------- fused per-row amax + quantize of h: fp32 -> i8 ints -----------
// One block per row, width = NV*2048. Row lives in regs: one global read pass.
template <int NV>
__global__ void hquant_kernel(const float* __restrict__ h, i8_t* __restrict__ hq,
                              float* __restrict__ scale_out) {
    const int row = blockIdx.x;
    const int tid = threadIdx.x;
    const int W = NV * 2048;
    const float* p = h + (size_t)row * W + tid * (NV * 8);
    float v[NV * 8];
#pragma unroll
    for (int it = 0; it < NV * 2; ++it) {
        v4fl a = *(const v4fl*)(p + it * 4);
#pragma unroll
        for (int j = 0; j < 4; ++j) v[it * 4 + j] = a[j];
    }
    float amax = 0.f;
#pragma unroll
    for (int j = 0; j < NV * 8; ++j) amax = fmaxf(amax, fabsf(v[j]));
#pragma unroll
    for (int off = 32; off > 0; off >>= 1) amax = fmaxf(amax, __shfl_xor(amax, off, 64));
    __shared__ __align__(16) float red[4];
    __shared__ float bsc;
    if ((tid & 63) == 0) red[tid >> 6] = amax;
    __syncthreads();
    if (tid == 0) {
        float m = fmaxf(fmaxf(red[0], red[1]), fmaxf(red[2], red[3]));
        m = fmaxf(m, 1e-5f);
        scale_out[row] = m / 127.f;
        bsc = 127.f / m;
    }
    __syncthreads();
    const float sc = bsc;
    i8_t* dst = hq + (size_t)row * W + tid * (NV * 8);
    v16c o;
#pragma unroll
    for (int j = 0; j < NV * 8; ++j) {
        float t = rintf(v[j] * sc);
        o[j] = (i8_t)(int)fminf(127.f, fmaxf(-127.f, t));
    }
    *(v16c*)dst = o;
}

// ---------------- per-row amax of h (fallback paths only) -------------------------
template <typename T, int NV>
__global__ void hamax_kernel(const T* __restrict__ h, float* __restrict__ scale_out,
                             float* __restrict__ recip_out) {
    const int row = blockIdx.x;
    const int tid = threadIdx.x;
    const T* p = h + (size_t)row * (NV * 2048);
    float amax = 0.f;
#pragma unroll
    for (int it = 0; it < NV; ++it) {
        const T* s = p + ((size_t)it * 256 + tid) * 8;
#pragma unroll
        for (int j = 0; j < 8; ++j) amax = fmaxf(amax, fabsf((float)s[j]));
    }
#pragma unroll
    for (int off = 32; off > 0; off >>= 1) amax = fmaxf(amax, __shfl_xor(amax, off, 64));
    __shared__ __align__(16) float red[4];
    if ((tid & 63) == 0) red[tid >> 6] = amax;
    __syncthreads();
    if (tid == 0) {
        float m = fmaxf(fmaxf(red[0], red[1]), fmaxf(red[2], red[3]));
        m = fmaxf(m, 1e-5f);
        scale_out[row] = m / 127.f;
        recip_out[row] = 127.f / m;
    }
}

// ---------------- GEMM: C[M,N] = A[M,K] * B[N,K]^T -> MFMA i8 (exact int math) ----
// m97 structure, i8: 128x128 tile, BK=64 i8 (64B rows), global_load_lds width-16,
// 2 barriers/K-step, kiters = K/64. Integer dot products are exact (|acc| < 2^24),
// so this is bit-identical to the hoisted-scale bf16 path it replaces.
// ASRC: 0 = A i8 via global_load_lds; 1 = A fp32 quantize-on-stage (reg fallback);
//       2 = A fp16 quantize-on-stage (reg fallback).
// EPI:  0 = out fp32 = acc*sw*rowscale; 1 = h fp16 = relu(...)^2; 2 = h fp32 = relu(...)^2.
template <int ASRC, int EPI>
__launch_bounds__(256, 2)
__global__ void gemm_bt(const void* __restrict__ Av, const i8_t* __restrict__ B,
                        void* __restrict__ Cv,
                        const float* __restrict__ rowscale,
                        const float* __restrict__ arecip,
                        const float* __restrict__ wscale,
                        int M, int N, int K) {
    __shared__ __align__(16) i8_t As[BM * BK];   // 8 KB, linear [128][64]
    __shared__ __align__(16) i8_t Bs[BN * BK];   // 8 KB

    const int tid = threadIdx.x;

    // XCD-aware bijective swizzle of the flattened block id (nwg % 8 == 0 here)
    const int gx = gridDim.x;
    const int nwg = gx * gridDim.y;
    int flat = blockIdx.y * gx + blockIdx.x;
    if ((nwg & 7) == 0) flat = (flat & 7) * (nwg >> 3) + (flat >> 3);
    const int n0 = (flat % gx) * BN;
    const int m0 = (flat / gx) * BM;

    // ---- staging addressing: chunk c = i*256 + tid; row = c>>2, col = (c&3)*16 ----
    const int srow = tid >> 2;              // 0..63
    const int scol = (tid & 3) * 16;        // i8 elements (== bytes)
    const i8_t* gB0 = B + (size_t)(n0 + srow) * K + scol;
    const i8_t* gB1 = B + (size_t)(n0 + 64 + srow) * K + scol;
    i8_t* lB0 = Bs + tid * 16;
    i8_t* lB1 = Bs + 4096 + tid * 16;

    const i8_t* gA0 = nullptr;
    const i8_t* gA1 = nullptr;
    i8_t* lA0 = As + tid * 16;
    i8_t* lA1 = As + 4096 + tid * 16;
    if (ASRC == 0) {
        gA0 = (const i8_t*)Av + (size_t)(m0 + srow) * K + scol;
        gA1 = (const i8_t*)Av + (size_t)(m0 + 64 + srow) * K + scol;
    }

    // reg-stage quantize fallback: thread owns row tid>>1, 32 i8 at (tid&1)*32
    const int qrow = tid >> 1;
    const int qcol = (tid & 1) * 32;
    const float* gA32 = (const float*)Av + (size_t)(m0 + qrow) * K + qcol;
    const half_t* gAh = (const half_t*)Av + (size_t)(m0 + qrow) * K + qcol;
    i8_t* qdst = As + qrow * BK + qcol;
    const float qsc = (ASRC != 0) ? arecip[m0 + qrow] : 0.f;

    // compute role: wave (wr,wc) owns 64x64; 4x4 of 16x16x64 tiles
    const int w = tid >> 6, l = tid & 63;
    const int wr = w >> 1, wc = w & 1;
    const int lrow = l & 15, lq = l >> 4;

    v4i acc[4][4];
#pragma unroll
    for (int a = 0; a < 4; ++a)
#pragma unroll
        for (int b = 0; b < 4; ++b) acc[a][b] = (v4i){0, 0, 0, 0};

    const int kiters = K / BK;
    for (int kt = 0; kt < kiters; ++kt) {
        const int off = kt * BK;
        v16c r0, r1;
        if (ASRC == 1) {
#pragma unroll
            for (int c = 0; c < 4; ++c) {
                v4fl f0 = *(const v4fl*)(gA32 + off + c * 4);
                v4fl f1 = *(const v4fl*)(gA32 + off + 16 + c * 4);
#pragma unroll
                for (int e = 0; e < 4; ++e) {
                    float t0 = rintf(f0[e] * qsc);
                    float t1 = rintf(f1[e] * qsc);
                    r0[c * 4 + e] = (i8_t)(int)fminf(127.f, fmaxf(-127.f, t0));
                    r1[c * 4 + e] = (i8_t)(int)fminf(127.f, fmaxf(-127.f, t1));
                }
            }
        } else if (ASRC == 2) {
#pragma unroll
            for (int c = 0; c < 2; ++c) {
                v8h h0 = *(const v8h*)(gAh + off + c * 8);
                v8h h1 = *(const v8h*)(gAh + off + 16 + c * 8);
#pragma unroll
                for (int e = 0; e < 8; ++e) {
                    float t0 = rintf((float)h0[e] * qsc);
                    float t1 = rintf((float)h1[e] * qsc);
                    r0[c * 8 + e] = (i8_t)(int)fminf(127.f, fmaxf(-127.f, t0));
                    r1[c * 8 + e] = (i8_t)(int)fminf(127.f, fmaxf(-127.f, t1));
                }
            }
        }
        __syncthreads();                       // all fragment reads of prev tile done
        gload16(gB0 + off, lB0);
        gload16(gB1 + off, lB1);
        if (ASRC == 0) {
            gload16(gA0 + off, lA0);
            gload16(gA1 + off, lA1);
        } else {
            *(v16c*)qdst = r0;
            *(v16c*)(qdst + 16) = r1;
        }
        __syncthreads();                       // compiler drains vmcnt/lgkm before barrier

        v4i af[4], bfr[4];
#pragma unroll
        for (int mi = 0; mi < 4; ++mi)
            af[mi] = *(const v4i*)(As + (wr * 64 + mi * 16 + lrow) * BK + lq * 16);
#pragma unroll
        for (int nj = 0; nj < 4; ++nj)
            bfr[nj] = *(const v4i*)(Bs + (wc * 64 + nj * 16 + lrow) * BK + lq * 16);
#pragma unroll
        for (int mi = 0; mi < 4; ++mi)
#pragma unroll
            for (int nj = 0; nj < 4; ++nj)
                acc[mi][nj] = __builtin_amdgcn_mfma_i32_16x16x64_i8(
                    af[mi], bfr[nj], acc[mi][nj], 0, 0, 0);
    }

    const float sw = wscale[0];   // pre-clipped mean|w|
#pragma unroll
    for (int mi = 0; mi < 4; ++mi) {
#pragma unroll
        for (int r = 0; r < 4; ++r) {
            const int row = m0 + wr * 64 + mi * 16 + lq * 4 + r;
            const float rs = sw * rowscale[row];
#pragma unroll
            for (int nj = 0; nj < 4; ++nj) {
                const int col = n0 + wc * 64 + nj * 16 + lrow;
                float v = (float)acc[mi][nj][r] * rs;   // exact: |acc| < 2^24
                if (EPI == 0) {
                    ((float*)Cv)[(size_t)row * N + col] = v;
                } else if (EPI == 1) {
                    v = fmaxf(v, 0.f); v = v * v;
                    ((half_t*)Cv)[(size_t)row * N + col] = (half_t)v;
                } else {
                    v = fmaxf(v, 0.f); v = v * v;
                    ((float*)Cv)[(size_t)row * N + col] = v;
                }
            }
        }
    }
}

extern "C" void kernel_launch(void* const* d_in, const int* in_sizes, int n_in,
                              void* d_out, int out_size, void* d_ws, size_t ws_size,
                              hipStream_t stream) {
    const float* x   = (const float*)d_in[0];   // [T, H] fp32
    const float* wup = (const float*)d_in[1];   // [I, H] fp32
    const float* wdn = (const float*)d_in[2];   // [H, I] fp32

    const int H = 2048;
    const int T = in_sizes[0] / H;              // 16384
    const int I = in_sizes[1] / H;              // 4096
    const long nw = (long)in_sizes[1];          // 8388608
    const float winv = 1.0f / (float)nw;

    char* p = (char*)d_ws;
    float* scales  = (float*)p;                 // 2 floats (pre-clipped s_up, s_dn)
    float* part_up = (float*)(p + 256);         // 256 floats
    float* part_dn = (float*)(p + 1280);        // 256 floats
    float* a_scale = (float*)(p + 2304);        // T
    float* h_scale = a_scale + T;               // T
    float* h_recip = h_scale + T;               // T
    size_t off = 2304 + (size_t)12 * T;
    off = (off + 255) & ~(size_t)255;
    i8_t* xq  = (i8_t*)(p + off); off += (size_t)T * H;
    off = (off + 255) & ~(size_t)255;
    i8_t* wqu = (i8_t*)(p + off); off += (size_t)I * H;
    off = (off + 255) & ~(size_t)255;
    i8_t* wqd = (i8_t*)(p + off); off += (size_t)H * I;
    off = (off + 255) & ~(size_t)255;
    void* h  = (void*)(p + off);
    i8_t* hq = (i8_t*)(p + off + (size_t)T * I * 4);

    const size_t need_full = off + (size_t)T * I * 5;   // h fp32 + hq i8
    const size_t need_h32  = off + (size_t)T * I * 4;   // h fp32 only
    const int mode = (ws_size == 0 || need_full <= ws_size) ? 0
                   : (need_h32 <= ws_size ? 1 : 2);

    // deterministic mean|w|: per-block partials, then fixed-order combine
    abssum_partial<<<256, 256, 0, stream>>>(wup, nw, part_up);
    abssum_partial<<<256, 256, 0, stream>>>(wdn, nw, part_dn);
    abssum_final<<<1, 128, 0, stream>>>(part_up, part_dn, scales, winv);

    int wblocks = (int)(nw / 2048);
    wquant_kernel<<<wblocks, 256, 0, stream>>>(wup, wqu, scales + 0);
    wquant_kernel<<<wblocks, 256, 0, stream>>>(wdn, wqd, scales + 1);

    aquant_kernel<<<T, 256, 0, stream>>>(x, xq, a_scale);

    if (mode == 0) {
        gemm_bt<0, 2><<<dim3(I / BN, T / BM), 256, 0, stream>>>(
            xq, wqu, h, a_scale, nullptr, scales + 0, T, I, H);
        hquant_kernel<2><<<T, 256, 0, stream>>>((const float*)h, hq, h_scale);
        gemm_bt<0, 0><<<dim3(H / BN, T / BM), 256, 0, stream>>>(
            hq, wqd, d_out, h_scale, nullptr, scales + 1, T, H, I);
    } else if (mode == 1) {
        gemm_bt<0, 2><<<dim3(I / BN, T / BM), 256, 0, stream>>>(
            xq, wqu, h, a_scale, nullptr, scales + 0, T, I, H);
        hamax_kernel<float, 2><<<T, 256, 0, stream>>>((const float*)h, h_scale, h_recip);
        gemm_bt<1, 0><<<dim3(H / BN, T / BM), 256, 0, stream>>>(
            h, wqd, d_out, h_scale, h_recip, scales + 1, T, H, I);
    } else {
        gemm_bt<0, 1><<<dim3(I / BN, T / BM), 256, 0, stream>>>(
            xq, wqu, h, a_scale, nullptr, scales + 0, T, I, H);
        hamax_kernel<half_t, 2><<<T, 256, 0, stream>>>((const half_t*)h, h_scale, h_recip);
        gemm_bt<2, 0><<<dim3(H / BN, T / BM), 256, 0, stream>>>(
            h, wqd, d_out, h_scale, h_recip, scales + 1, T, H, I);
    }
}

// Round 3
// 628.812 us; speedup vs baseline: 1.7171x; 1.0772x over previous
//
#include <hip/hip_runtime.h>
#include <hip/hip_bf16.h>

typedef signed char i8_t;
typedef _Float16 half_t;
typedef float v4fl __attribute__((ext_vector_type(4)));
typedef _Float16 v8h __attribute__((ext_vector_type(8)));
typedef int v4i __attribute__((ext_vector_type(4)));
typedef signed char v8c __attribute__((ext_vector_type(8)));
typedef signed char v16c __attribute__((ext_vector_type(16)));

__device__ __forceinline__ float ternqf(float w, float s) {
    float q = rintf(w / s);                 // true division: match jnp boundary
    return fminf(1.f, fmaxf(-1.f, q));
}

// async global->LDS, 16 bytes per lane. LDS dest must be wave-uniform base + lane*16.
__device__ __forceinline__ void gload16(const void* g, void* l) {
    __builtin_amdgcn_global_load_lds(
        (const __attribute__((address_space(1))) void*)g,
        (__attribute__((address_space(3))) void*)l, 16, 0, 0);
}

// ---------------- stage 1: per-block partial sum of |w| (deterministic) ----------
__global__ void abssum_partial(const float* __restrict__ w, long n,
                               float* __restrict__ partial) {
    long i0 = ((long)blockIdx.x * 256 + threadIdx.x) * 8;
    long stride = (long)gridDim.x * 256 * 8;
    float s = 0.f;
    for (long i = i0; i < n; i += stride) {
        v4fl a = *(const v4fl*)(w + i);
        v4fl b = *(const v4fl*)(w + i + 4);
#pragma unroll
        for (int j = 0; j < 4; ++j) s += fabsf(a[j]) + fabsf(b[j]);
    }
#pragma unroll
    for (int off = 32; off > 0; off >>= 1) s += __shfl_down(s, off, 64);
    __shared__ __align__(16) float red[4];
    if ((threadIdx.x & 63) == 0) red[threadIdx.x >> 6] = s;
    __syncthreads();
    if (threadIdx.x == 0)
        partial[blockIdx.x] = (red[0] + red[1]) + (red[2] + red[3]);
}

// ---------------- stage 2: combine 256 partials per matrix, fixed order -----------
__global__ void abssum_final(const float* __restrict__ part_up,
                             const float* __restrict__ part_dn,
                             float* __restrict__ scales, float inv) {
    const int wv = threadIdx.x >> 6;
    const int l = threadIdx.x & 63;
    const float* part = wv ? part_dn : part_up;
    float s = ((part[l] + part[l + 64]) + (part[l + 128] + part[l + 192]));
#pragma unroll
    for (int off = 32; off > 0; off >>= 1) s += __shfl_down(s, off, 64);
    if (l == 0) scales[wv] = fmaxf(s * inv, 1e-5f);
}

// ---------------- ternary weight quant fp32 -> i8 {-1,0,1} ----------------
__global__ void wquant_kernel(const float* __restrict__ w, i8_t* __restrict__ wq,
                              const float* __restrict__ scale) {
    float s = scale[0];
    long i = ((long)blockIdx.x * 256 + threadIdx.x) * 8;
    v4fl a = *(const v4fl*)(w + i);
    v4fl b = *(const v4fl*)(w + i + 4);
    v8c o;
#pragma unroll
    for (int j = 0; j < 4; ++j) {
        o[j]     = (i8_t)(int)ternqf(a[j], s);
        o[j + 4] = (i8_t)(int)ternqf(b[j], s);
    }
    *(v8c*)(wq + i) = o;
}

// ---------------- per-token act quant fp32 -> i8 ints, width 2048 ----------------
__global__ void aquant_kernel(const float* __restrict__ src, i8_t* __restrict__ dst,
                              float* __restrict__ scale_out) {
    const int row = blockIdx.x;
    const int tid = threadIdx.x;
    const float* p = src + (size_t)row * 2048;
    float v[8];
    {
        v4fl a = *(const v4fl*)(p + tid * 8);
        v4fl b = *(const v4fl*)(p + tid * 8 + 4);
#pragma unroll
        for (int j = 0; j < 4; ++j) { v[j] = a[j]; v[j + 4] = b[j]; }
    }
    float amax = 0.f;
#pragma unroll
    for (int j = 0; j < 8; ++j) amax = fmaxf(amax, fabsf(v[j]));
#pragma unroll
    for (int off = 32; off > 0; off >>= 1) amax = fmaxf(amax, __shfl_xor(amax, off, 64));
    __shared__ __align__(16) float red[4];
    __shared__ float bsc;
    if ((tid & 63) == 0) red[tid >> 6] = amax;
    __syncthreads();
    if (tid == 0) {
        float m = fmaxf(fmaxf(red[0], red[1]), fmaxf(red[2], red[3]));
        m = fmaxf(m, 1e-5f);
        scale_out[row] = m / 127.f;
        bsc = 127.f / m;
    }
    __syncthreads();
    float sc = bsc;
    v8c o;
#pragma unroll
    for (int j = 0; j < 8; ++j) {
        float t = rintf(v[j] * sc);
        o[j] = (i8_t)(int)fminf(127.f, fmaxf(-127.f, t));
    }
    *(v8c*)(dst + (size_t)row * 2048 + tid * 8) = o;
}

// ---------------- fused per-row amax + quantize of h: fp32 -> i8 ints -----------
template <int NV>
__global__ void hquant_kernel(const float* __restrict__ h, i8_t* __restrict__ hq,
                              float* __restrict__ scale_out) {
    const int row = blockIdx.x;
    const int tid = threadIdx.x;
    const int W = NV * 2048;
    const float* p = h + (size_t)row * W + tid * (NV * 8);
    float v[NV * 8];
#pragma unroll
    for (int it = 0; it < NV * 2; ++it) {
        v4fl a = *(const v4fl*)(p + it * 4);
#pragma unroll
        for (int j = 0; j < 4; ++j) v[it * 4 + j] = a[j];
    }
    float amax = 0.f;
#pragma unroll
    for (int j = 0; j < NV * 8; ++j) amax = fmaxf(amax, fabsf(v[j]));
#pragma unroll
    for (int off = 32; off > 0; off >>= 1) amax = fmaxf(amax, __shfl_xor(amax, off, 64));
    __shared__ __align__(16) float red[4];
    __shared__ float bsc;
    if ((tid & 63) == 0) red[tid >> 6] = amax;
    __syncthreads();
    if (tid == 0) {
        float m = fmaxf(fmaxf(red[0], red[1]), fmaxf(red[2], red[3]));
        m = fmaxf(m, 1e-5f);
        scale_out[row] = m / 127.f;
        bsc = 127.f / m;
    }
    __syncthreads();
    const float sc = bsc;
    i8_t* dst = hq + (size_t)row * W + tid * (NV * 8);
    v16c o;
#pragma unroll
    for (int j = 0; j < NV * 8; ++j) {
        float t = rintf(v[j] * sc);
        o[j] = (i8_t)(int)fminf(127.f, fmaxf(-127.f, t));
    }
    *(v16c*)dst = o;
}

// ---------------- per-row amax of h (fallback paths only) -------------------------
template <typename T, int NV>
__global__ void hamax_kernel(const T* __restrict__ h, float* __restrict__ scale_out,
                             float* __restrict__ recip_out) {
    const int row = blockIdx.x;
    const int tid = threadIdx.x;
    const T* p = h + (size_t)row * (NV * 2048);
    float amax = 0.f;
#pragma unroll
    for (int it = 0; it < NV; ++it) {
        const T* s = p + ((size_t)it * 256 + tid) * 8;
#pragma unroll
        for (int j = 0; j < 8; ++j) amax = fmaxf(amax, fabsf((float)s[j]));
    }
#pragma unroll
    for (int off = 32; off > 0; off >>= 1) amax = fmaxf(amax, __shfl_xor(amax, off, 64));
    __shared__ __align__(16) float red[4];
    if ((tid & 63) == 0) red[tid >> 6] = amax;
    __syncthreads();
    if (tid == 0) {
        float m = fmaxf(fmaxf(red[0], red[1]), fmaxf(red[2], red[3]));
        m = fmaxf(m, 1e-5f);
        scale_out[row] = m / 127.f;
        recip_out[row] = 127.f / m;
    }
}

// =================================================================================
// 256x256 8-phase i8 GEMM (T2+T3+T4+T5), C[M,N] = A[M,K] * B[N,K]^T, exact int math.
// 512 thr = 8 waves (2Mx4N), per-wave C = 128x64. BK=128 i8. LDS 128KB (2 K-tile bufs).
// Staging: global_load_lds w16, LINEAR dest; swizzle col ^= (row&7)<<4 applied to the
// GLOBAL source and to the ds_read address (rule #21: both-sides-or-neither).
// Per K-tile, 4 phases x {ds_read | prefetch-issue | barrier | MFMA x16 | barrier}:
//   ph0: read B all (8xb128) + A ks0 (8xb128); MFMA A.ks0 x B[0,1].ks0
//   ph1: issue B(t+2) (B-of-t reads ended ph0);  MFMA A.ks0 x B[2,3].ks0
//   ph2: read A ks1;                             MFMA A.ks1 x B[0,1].ks1
//   ph3: issue A(t+2) (A-of-t reads ended ph2);  MFMA A.ks1 x B[2,3].ks1
// Tile end: s_waitcnt vmcnt(8) -> retires tile t+1's 8 loads, keeps t+2's 8 in flight.
// =================================================================================
__device__ __forceinline__ void stage_tile256(const i8_t* __restrict__ g, int K,
                                              i8_t* l, int tid) {
#pragma unroll
    for (int i = 0; i < 4; ++i) {
        const int c = i * 512 + tid;            // chunk: 16B units, LDS-linear
        const int r = c >> 3;                   // tile row 0..255
        const int lc = (((c & 7) ^ (r & 7)) << 4);  // inverse-swizzled global col
        gload16(g + (size_t)r * K + lc, l + c * 16);
    }
}

#define MIDBAR() do { \
    __builtin_amdgcn_s_barrier(); \
    __builtin_amdgcn_sched_barrier(0); \
    asm volatile("s_waitcnt lgkmcnt(0)" ::: "memory"); \
    __builtin_amdgcn_sched_barrier(0); } while (0)

#define ENDBAR() do { \
    __builtin_amdgcn_sched_barrier(0); \
    __builtin_amdgcn_s_barrier(); \
    __builtin_amdgcn_sched_barrier(0); } while (0)

template <int EPI>   // 0: out fp32 = acc*sw*rowscale; 2: h fp32 = relu(...)^2
__launch_bounds__(512, 2)
__global__ void gemm_bt8(const i8_t* __restrict__ A, const i8_t* __restrict__ B,
                         void* __restrict__ Cv,
                         const float* __restrict__ rowscale,
                         const float* __restrict__ wscale,
                         int M, int N, int K) {
    __shared__ __align__(16) i8_t smem[131072];   // [2 buf][ A 32KB | B 32KB ]

    const int tid = threadIdx.x;

    // XCD-aware bijective swizzle (grids here are multiples of 8)
    const int gx = gridDim.x;
    const int nwg = gx * gridDim.y;
    int flat = blockIdx.y * gx + blockIdx.x;
    if ((nwg & 7) == 0) flat = (flat & 7) * (nwg >> 3) + (flat >> 3);
    const int n0 = (flat % gx) * 256;
    const int m0 = (flat / gx) * 256;

    const i8_t* gA = A + (size_t)m0 * K;
    const i8_t* gB = B + (size_t)n0 * K;

    const int w = tid >> 6, l = tid & 63;
    const int wr = w >> 2, wc = w & 3;           // wave tile: rows wr*128, cols wc*64
    const int lrow = l & 15, lq = l >> 4;
    const int swz = (lrow & 7) << 4;
    const int c0 = (lq << 4) ^ swz;              // swizzled k-byte base (ks0)
    const int aoff0 = ((wr * 128 + lrow) << 7) + c0;   // bit6 of row part is 0 -> ^64 ok
    const int boff0 = ((wc * 64 + lrow) << 7) + c0;

    v4i acc[8][4];
#pragma unroll
    for (int a = 0; a < 8; ++a)
#pragma unroll
        for (int b = 0; b < 4; ++b) acc[a][b] = (v4i){0, 0, 0, 0};

    const int NT = K >> 7;
    // prologue: tiles 0 and 1 (B then A each; vmcnt counts: oldest 8 = tile0)
    stage_tile256(gB, K, smem + 32768, tid);
    stage_tile256(gA, K, smem, tid);
    stage_tile256(gB + 128, K, smem + 65536 + 32768, tid);
    stage_tile256(gA + 128, K, smem + 65536, tid);
    asm volatile("s_waitcnt vmcnt(8)" ::: "memory");   // tile0 resident; tile1 in flight
    __builtin_amdgcn_s_barrier();
    __builtin_amdgcn_sched_barrier(0);

    for (int t = 0; t < NT; ++t) {
        i8_t* Ab = smem + ((t & 1) << 16);
        i8_t* Bb = Ab + 32768;
        const bool pf = (t + 2 < NT);

        v4i af[8], bf[4][2];
        // ---- ph0: read all B frags + A ks0 frags ----
#pragma unroll
        for (int nj = 0; nj < 4; ++nj) {
            bf[nj][0] = *(const v4i*)(Bb + (boff0 + (nj << 11)));
            bf[nj][1] = *(const v4i*)(Bb + ((boff0 + (nj << 11)) ^ 64));
        }
#pragma unroll
        for (int mi = 0; mi < 8; ++mi)
            af[mi] = *(const v4i*)(Ab + (aoff0 + (mi << 11)));
        MIDBAR();
        __builtin_amdgcn_s_setprio(1);
#pragma unroll
        for (int mi = 0; mi < 8; ++mi)
#pragma unroll
            for (int nj = 0; nj < 2; ++nj)
                acc[mi][nj] = __builtin_amdgcn_mfma_i32_16x16x64_i8(
                    af[mi], bf[nj][0], acc[mi][nj], 0, 0, 0);
        __builtin_amdgcn_s_setprio(0);
        ENDBAR();

        // ---- ph1: issue B(t+2) into this buffer (B reads of tile t done at ph0) ----
        if (pf) stage_tile256(gB + (size_t)(t + 2) * 128, K, Bb, tid);
        MIDBAR();
        __builtin_amdgcn_s_setprio(1);
#pragma unroll
        for (int mi = 0; mi < 8; ++mi)
#pragma unroll
            for (int nj = 2; nj < 4; ++nj)
                acc[mi][nj] = __builtin_amdgcn_mfma_i32_16x16x64_i8(
                    af[mi], bf[nj][0], acc[mi][nj], 0, 0, 0);
        __builtin_amdgcn_s_setprio(0);
        ENDBAR();

        // ---- ph2: read A ks1 frags ----
#pragma unroll
        for (int mi = 0; mi < 8; ++mi)
            af[mi] = *(const v4i*)(Ab + ((aoff0 + (mi << 11)) ^ 64));
        MIDBAR();
        __builtin_amdgcn_s_setprio(1);
#pragma unroll
        for (int mi = 0; mi < 8; ++mi)
#pragma unroll
            for (int nj = 0; nj < 2; ++nj)
                acc[mi][nj] = __builtin_amdgcn_mfma_i32_16x16x64_i8(
                    af[mi], bf[nj][1], acc[mi][nj], 0, 0, 0);
        __builtin_amdgcn_s_setprio(0);
        ENDBAR();

        // ---- ph3: issue A(t+2) (A reads of tile t done at ph2) ----
        if (pf) stage_tile256(gA + (size_t)(t + 2) * 128, K, Ab, tid);
        MIDBAR();
        __builtin_amdgcn_s_setprio(1);
#pragma unroll
        for (int mi = 0; mi < 8; ++mi)
#pragma unroll
            for (int nj = 2; nj < 4; ++nj)
                acc[mi][nj] = __builtin_amdgcn_mfma_i32_16x16x64_i8(
                    af[mi], bf[nj][1], acc[mi][nj], 0, 0, 0);
        __builtin_amdgcn_s_setprio(0);
        __builtin_amdgcn_sched_barrier(0);
        // tile end: retire tile t+1's loads, keep t+2's 8 in flight (never drain-0)
        if (pf) {
            asm volatile("s_waitcnt vmcnt(8)" ::: "memory");
        } else if (t + 1 < NT) {
            asm volatile("s_waitcnt vmcnt(0)" ::: "memory");
        }
        if (t + 1 < NT) {
            __builtin_amdgcn_s_barrier();
            __builtin_amdgcn_sched_barrier(0);
        }
    }

    const float sw = wscale[0];   // pre-clipped mean|w|
#pragma unroll
    for (int mi = 0; mi < 8; ++mi) {
#pragma unroll
        for (int r = 0; r < 4; ++r) {
            const int row = m0 + wr * 128 + mi * 16 + lq * 4 + r;
            const float rs = sw * rowscale[row];
#pragma unroll
            for (int nj = 0; nj < 4; ++nj) {
                const int col = n0 + wc * 64 + nj * 16 + lrow;
                float v = (float)acc[mi][nj][r] * rs;   // exact: |acc| < 2^24
                if (EPI == 0) {
                    ((float*)Cv)[(size_t)row * N + col] = v;
                } else {
                    v = fmaxf(v, 0.f); v = v * v;
                    ((float*)Cv)[(size_t)row * N + col] = v;
                }
            }
        }
    }
}

// ---------------- 128x128 m97-structure i8 GEMM (fallback paths) ------------------
template <int ASRC, int EPI>
__launch_bounds__(256, 2)
__global__ void gemm_bt(const void* __restrict__ Av, const i8_t* __restrict__ B,
                        void* __restrict__ Cv,
                        const float* __restrict__ rowscale,
                        const float* __restrict__ arecip,
                        const float* __restrict__ wscale,
                        int M, int N, int K) {
    __shared__ __align__(16) i8_t As[128 * 64];
    __shared__ __align__(16) i8_t Bs[128 * 64];

    const int tid = threadIdx.x;
    const int gx = gridDim.x;
    const int nwg = gx * gridDim.y;
    int flat = blockIdx.y * gx + blockIdx.x;
    if ((nwg & 7) == 0) flat = (flat & 7) * (nwg >> 3) + (flat >> 3);
    const int n0 = (flat % gx) * 128;
    const int m0 = (flat / gx) * 128;

    const int srow = tid >> 2;
    const int scol = (tid & 3) * 16;
    const i8_t* gB0 = B + (size_t)(n0 + srow) * K + scol;
    const i8_t* gB1 = B + (size_t)(n0 + 64 + srow) * K + scol;
    i8_t* lB0 = Bs + tid * 16;
    i8_t* lB1 = Bs + 4096 + tid * 16;

    const i8_t* gA0 = nullptr;
    const i8_t* gA1 = nullptr;
    i8_t* lA0 = As + tid * 16;
    i8_t* lA1 = As + 4096 + tid * 16;
    if (ASRC == 0) {
        gA0 = (const i8_t*)Av + (size_t)(m0 + srow) * K + scol;
        gA1 = (const i8_t*)Av + (size_t)(m0 + 64 + srow) * K + scol;
    }

    const int qrow = tid >> 1;
    const int qcol = (tid & 1) * 32;
    const float* gA32 = (const float*)Av + (size_t)(m0 + qrow) * K + qcol;
    const half_t* gAh = (const half_t*)Av + (size_t)(m0 + qrow) * K + qcol;
    i8_t* qdst = As + qrow * 64 + qcol;
    const float qsc = (ASRC != 0) ? arecip[m0 + qrow] : 0.f;

    const int w = tid >> 6, l = tid & 63;
    const int wr = w >> 1, wc = w & 1;
    const int lrow = l & 15, lq = l >> 4;

    v4i acc[4][4];
#pragma unroll
    for (int a = 0; a < 4; ++a)
#pragma unroll
        for (int b = 0; b < 4; ++b) acc[a][b] = (v4i){0, 0, 0, 0};

    const int kiters = K / 64;
    for (int kt = 0; kt < kiters; ++kt) {
        const int off = kt * 64;
        v16c r0, r1;
        if (ASRC == 1) {
#pragma unroll
            for (int c = 0; c < 4; ++c) {
                v4fl f0 = *(const v4fl*)(gA32 + off + c * 4);
                v4fl f1 = *(const v4fl*)(gA32 + off + 16 + c * 4);
#pragma unroll
                for (int e = 0; e < 4; ++e) {
                    float t0 = rintf(f0[e] * qsc);
                    float t1 = rintf(f1[e] * qsc);
                    r0[c * 4 + e] = (i8_t)(int)fminf(127.f, fmaxf(-127.f, t0));
                    r1[c * 4 + e] = (i8_t)(int)fminf(127.f, fmaxf(-127.f, t1));
                }
            }
        } else if (ASRC == 2) {
#pragma unroll
            for (int c = 0; c < 2; ++c) {
                v8h h0 = *(const v8h*)(gAh + off + c * 8);
                v8h h1 = *(const v8h*)(gAh + off + 16 + c * 8);
#pragma unroll
                for (int e = 0; e < 8; ++e) {
                    float t0 = rintf((float)h0[e] * qsc);
                    float t1 = rintf((float)h1[e] * qsc);
                    r0[c * 8 + e] = (i8_t)(int)fminf(127.f, fmaxf(-127.f, t0));
                    r1[c * 8 + e] = (i8_t)(int)fminf(127.f, fmaxf(-127.f, t1));
                }
            }
        }
        __syncthreads();
        gload16(gB0 + off, lB0);
        gload16(gB1 + off, lB1);
        if (ASRC == 0) {
            gload16(gA0 + off, lA0);
            gload16(gA1 + off, lA1);
        } else {
            *(v16c*)qdst = r0;
            *(v16c*)(qdst + 16) = r1;
        }
        __syncthreads();

        v4i af[4], bfr[4];
#pragma unroll
        for (int mi = 0; mi < 4; ++mi)
            af[mi] = *(const v4i*)(As + (wr * 64 + mi * 16 + lrow) * 64 + lq * 16);
#pragma unroll
        for (int nj = 0; nj < 4; ++nj)
            bfr[nj] = *(const v4i*)(Bs + (wc * 64 + nj * 16 + lrow) * 64 + lq * 16);
#pragma unroll
        for (int mi = 0; mi < 4; ++mi)
#pragma unroll
            for (int nj = 0; nj < 4; ++nj)
                acc[mi][nj] = __builtin_amdgcn_mfma_i32_16x16x64_i8(
                    af[mi], bfr[nj], acc[mi][nj], 0, 0, 0);
    }

    const float sw = wscale[0];
#pragma unroll
    for (int mi = 0; mi < 4; ++mi) {
#pragma unroll
        for (int r = 0; r < 4; ++r) {
            const int row = m0 + wr * 64 + mi * 16 + lq * 4 + r;
            const float rs = sw * rowscale[row];
#pragma unroll
            for (int nj = 0; nj < 4; ++nj) {
                const int col = n0 + wc * 64 + nj * 16 + lrow;
                float v = (float)acc[mi][nj][r] * rs;
                if (EPI == 0) {
                    ((float*)Cv)[(size_t)row * N + col] = v;
                } else if (EPI == 1) {
                    v = fmaxf(v, 0.f); v = v * v;
                    ((half_t*)Cv)[(size_t)row * N + col] = (half_t)v;
                } else {
                    v = fmaxf(v, 0.f); v = v * v;
                    ((float*)Cv)[(size_t)row * N + col] = v;
                }
            }
        }
    }
}

extern "C" void kernel_launch(void* const* d_in, const int* in_sizes, int n_in,
                              void* d_out, int out_size, void* d_ws, size_t ws_size,
                              hipStream_t stream) {
    const float* x   = (const float*)d_in[0];   // [T, H] fp32
    const float* wup = (const float*)d_in[1];   // [I, H] fp32
    const float* wdn = (const float*)d_in[2];   // [H, I] fp32

    const int H = 2048;
    const int T = in_sizes[0] / H;              // 16384
    const int I = in_sizes[1] / H;              // 4096
    const long nw = (long)in_sizes[1];          // 8388608
    const float winv = 1.0f / (float)nw;

    char* p = (char*)d_ws;
    float* scales  = (float*)p;
    float* part_up = (float*)(p + 256);
    float* part_dn = (float*)(p + 1280);
    float* a_scale = (float*)(p + 2304);
    float* h_scale = a_scale + T;
    float* h_recip = h_scale + T;
    size_t off = 2304 + (size_t)12 * T;
    off = (off + 255) & ~(size_t)255;
    i8_t* xq  = (i8_t*)(p + off); off += (size_t)T * H;
    off = (off + 255) & ~(size_t)255;
    i8_t* wqu = (i8_t*)(p + off); off += (size_t)I * H;
    off = (off + 255) & ~(size_t)255;
    i8_t* wqd = (i8_t*)(p + off); off += (size_t)H * I;
    off = (off + 255) & ~(size_t)255;
    void* h  = (void*)(p + off);
    i8_t* hq = (i8_t*)(p + off + (size_t)T * I * 4);

    const size_t need_full = off + (size_t)T * I * 5;
    const size_t need_h32  = off + (size_t)T * I * 4;
    const int mode = (ws_size == 0 || need_full <= ws_size) ? 0
                   : (need_h32 <= ws_size ? 1 : 2);
    const bool big_ok = (T % 256 == 0) && (I % 256 == 0) && (H % 256 == 0) &&
                        (H >= 256) && (I >= 256);

    abssum_partial<<<256, 256, 0, stream>>>(wup, nw, part_up);
    abssum_partial<<<256, 256, 0, stream>>>(wdn, nw, part_dn);
    abssum_final<<<1, 128, 0, stream>>>(part_up, part_dn, scales, winv);

    int wblocks = (int)(nw / 2048);
    wquant_kernel<<<wblocks, 256, 0, stream>>>(wup, wqu, scales + 0);
    wquant_kernel<<<wblocks, 256, 0, stream>>>(wdn, wqd, scales + 1);

    aquant_kernel<<<T, 256, 0, stream>>>(x, xq, a_scale);

    if (mode == 0 && big_ok) {
        gemm_bt8<2><<<dim3(I / 256, T / 256), 512, 0, stream>>>(
            xq, wqu, h, a_scale, scales + 0, T, I, H);
        hquant_kernel<2><<<T, 256, 0, stream>>>((const float*)h, hq, h_scale);
        gemm_bt8<0><<<dim3(H / 256, T / 256), 512, 0, stream>>>(
            hq, wqd, d_out, h_scale, scales + 1, T, H, I);
    } else if (mode == 0) {
        gemm_bt<0, 2><<<dim3(I / 128, T / 128), 256, 0, stream>>>(
            xq, wqu, h, a_scale, nullptr, scales + 0, T, I, H);
        hquant_kernel<2><<<T, 256, 0, stream>>>((const float*)h, hq, h_scale);
        gemm_bt<0, 0><<<dim3(H / 128, T / 128), 256, 0, stream>>>(
            hq, wqd, d_out, h_scale, nullptr, scales + 1, T, H, I);
    } else if (mode == 1) {
        gemm_bt<0, 2><<<dim3(I / 128, T / 128), 256, 0, stream>>>(
            xq, wqu, h, a_scale, nullptr, scales + 0, T, I, H);
        hamax_kernel<float, 2><<<T, 256, 0, stream>>>((const float*)h, h_scale, h_recip);
        gemm_bt<1, 0><<<dim3(H / 128, T / 128), 256, 0, stream>>>(
            h, wqd, d_out, h_scale, h_recip, scales + 1, T, H, I);
    } else {
        gemm_bt<0, 1><<<dim3(I / 128, T / 128), 256, 0, stream>>>(
            xq, wqu, h, a_scale, nullptr, scales + 0, T, I, H);
        hamax_kernel<half_t, 2><<<T, 256, 0, stream>>>((const half_t*)h, h_scale, h_recip);
        gemm_bt<2, 0><<<dim3(H / 128, T / 128), 256, 0, stream>>>(
            h, wqd, d_out, h_scale, h_recip, scales + 1, T, H, I);
    }
}